// Round 1
// baseline (4147.564 us; speedup 1.0000x reference)
//
#include <hip/hip_runtime.h>
#include <stdint.h>

// Net_11587821765063: sequential SNN scan, T=1000 steps.
// Output = spike_out (T, 1, COUT) float32 only; w / traces not returned.
//
// Key reductions of the reference math:
//  - potentiation p[t][i] = 2 if x[t][i] else (1 if (t==0 or x[t-1][i]) else 0)
//    (t==0: cin starts 0 -> min(0+1,31)=1 for non-firing cols -> LUT[30]=+1)
//  - depression for row o at step t = -x[t][i] iff (!spike[t][o] && spike_prev[o]),
//    with spike_prev initialized TRUE at t=0 (cout 0->1 -> LUT[28]=-1).
//  - prohibit[t] = 11250 iff any spike at t-1 (grid-wide 1-bit OR).
//
// Layout: 128 blocks x 5 waves. Waves 0..3 each own one output row
// (row = blk*4 + wave); each lane owns 13 columns of w in registers
// (784 padded to 832 = 64*13). Wave 4 is the sync wave: gathers per-block
// spike flags (device-scope atomics) and publishes prohibit via LDS.

#define T_STEPS 1000
#define CIN     784
#define COUT    512
#define CPL     13           // columns per lane (64*13 = 832 >= 784)
#define NBLK    128
#define ROWS_PER_BLK 4
#define VTHR_F   12500.0f
#define PROHIB_F 11250.0f

#define SLOTS_WORDS (T_STEPS * NBLK)          // uint32 per (t, block)
#define SLOTS_BYTES (SLOTS_WORDS * 4)         // 512000 B
#define CODE_OFFSET 524288                    // 512 KiB, 16B-aligned
#define CODE_BYTES  (T_STEPS * 64 * 16)       // 1,024,000 B

// ---- prep: pack per-(t,lane) 16-byte code slot: byte j (j<13) encodes
// column col = lane*13+j:  bit0 = x[t][col], bits[2:1] = potentiation p.
__global__ __launch_bounds__(256) void prep_kernel(const int* __restrict__ x,
                                                   uint8_t* __restrict__ code) {
    int gid = blockIdx.x * blockDim.x + threadIdx.x;   // one per (t, lane)
    if (gid >= T_STEPS * 64) return;
    int t = gid >> 6;
    int lane = gid & 63;
    uint32_t wds[4] = {0u, 0u, 0u, 0u};
    #pragma unroll
    for (int j = 0; j < CPL; ++j) {
        int col = lane * CPL + j;
        uint32_t b = 0u;
        if (col < CIN) {
            int xc = x[t * CIN + col];
            int xp = (t > 0) ? x[(t - 1) * CIN + col] : 0;
            int p = xc ? 2 : ((t == 0) ? 1 : (xp ? 1 : 0));
            b = (uint32_t)((xc & 1) | (p << 1));
        }
        wds[j >> 2] |= b << ((j & 3) * 8);
    }
    ((uint4*)code)[gid] = make_uint4(wds[0], wds[1], wds[2], wds[3]);
}

__global__ __launch_bounds__(320) void snn_kernel(const float* __restrict__ weight,
                                                  const uint8_t* __restrict__ code,
                                                  uint32_t* __restrict__ slots,
                                                  float* __restrict__ out) {
    __shared__ float sh_proh[2];
    const int tid  = threadIdx.x;
    const int wave = tid >> 6;
    const int lane = tid & 63;
    const int blk  = blockIdx.x;

    if (wave < ROWS_PER_BLK) {
        // ---------------- compute wave: one output row ----------------
        const int row = blk * ROWS_PER_BLK + wave;
        float w[CPL];
        #pragma unroll
        for (int j = 0; j < CPL; ++j) {
            int col = lane * CPL + j;
            w[j] = (col < CIN) ? weight[row * CIN + col] : 0.0f;
        }
        float mem = 0.0f;
        bool prevspike = true;   // t=0: cout 0->1 => depression gate open
        const uint4* code4 = (const uint4*)code;
        uint4 cw = code4[lane];  // codes for t=0 (prefetched)

        for (int t = 0; t < T_STEPS; ++t) {
            uint32_t cwd[4] = {cw.x, cw.y, cw.z, cw.w};
            float xf[CPL], pf[CPL];
            float dot = 0.0f;
            #pragma unroll
            for (int j = 0; j < CPL; ++j) {
                uint32_t c = (cwd[j >> 2] >> ((j & 3) * 8)) & 0xFFu;
                xf[j] = (float)(c & 1u);
                pf[j] = (float)(c >> 1);
                dot += xf[j] * w[j];     // x is exactly 0/1 -> product exact
            }
            // prefetch next step's codes; consumed after the barrier next iter
            uint4 cw_next = (t + 1 < T_STEPS) ? code4[(t + 1) * 64 + lane]
                                              : make_uint4(0u, 0u, 0u, 0u);
            // full-wave butterfly: every lane ends with the row dot
            #pragma unroll
            for (int off = 32; off >= 1; off >>= 1)
                dot += __shfl_xor(dot, off, 64);

            __syncthreads();            // A_t: sh_proh[t&1] is ready
            float proh = sh_proh[t & 1];

            float m = mem + dot;        // match reference op order exactly
            m = m - proh;
            m = fmaxf(m, 0.0f);
            bool spike = (m >= VTHR_F);
            mem = spike ? 0.0f : m;

            if (lane == 0) {
                // publish arrival bit + spike bit for this wave (device scope)
                uint32_t val = (1u << wave) | (spike ? (0x100u << wave) : 0u);
                __hip_atomic_fetch_or(&slots[t * NBLK + blk], val,
                                      __ATOMIC_RELAXED, __HIP_MEMORY_SCOPE_AGENT);
                out[t * COUT + row] = spike ? 1.0f : 0.0f;
            }

            float sF = spike ? 1.0f : 0.0f;
            float dF = (!spike && prevspike) ? 1.0f : 0.0f;  // mutually exclusive
            prevspike = spike;
            #pragma unroll
            for (int j = 0; j < CPL; ++j) {
                float delta = sF * pf[j] - dF * xf[j];       // exact small ints
                w[j] = fminf(fmaxf(w[j] + delta, 0.0f), 127.0f);
            }
            cw = cw_next;
        }
    } else {
        // ---------------- sync wave: gather prohibit flag ----------------
        for (int t = 0; t < T_STEPS; ++t) {
            if (t == 0 && lane == 0) sh_proh[0] = 0.0f;  // reg starts all-false
            __syncthreads();            // A_t (matches compute waves)
            if (t + 1 < T_STEPS) {
                const uint32_t* sl = slots + (size_t)t * NBLK;
                uint32_t v0, v1;
                bool ok;
                do {
                    v0 = __hip_atomic_load(&sl[lane], __ATOMIC_RELAXED,
                                           __HIP_MEMORY_SCOPE_AGENT);
                    v1 = __hip_atomic_load(&sl[64 + lane], __ATOMIC_RELAXED,
                                           __HIP_MEMORY_SCOPE_AGENT);
                    ok = ((v0 & 0xFu) == 0xFu) && ((v1 & 0xFu) == 0xFu);
                } while (!__all(ok));
                int any = __any((int)(((v0 | v1) & 0xF00u) != 0u));
                if (lane == 0) sh_proh[(t + 1) & 1] = any ? PROHIB_F : 0.0f;
            }
        }
    }
}

extern "C" void kernel_launch(void* const* d_in, const int* in_sizes, int n_in,
                              void* d_out, int out_size, void* d_ws, size_t ws_size,
                              hipStream_t stream) {
    const int*   x      = (const int*)d_in[0];     // (T,1,CIN) int32
    const float* weight = (const float*)d_in[1];   // (COUT,CIN) f32
    float* out = (float*)d_out;                    // (T,1,COUT) f32

    uint32_t* slots = (uint32_t*)d_ws;
    uint8_t*  code  = (uint8_t*)d_ws + CODE_OFFSET;

    // slots must start at 0 every launch (ws re-poisoned to 0xAA)
    hipMemsetAsync(slots, 0, SLOTS_BYTES, stream);

    int prep_threads = T_STEPS * 64;
    prep_kernel<<<(prep_threads + 255) / 256, 256, 0, stream>>>(x, code);
    snn_kernel<<<NBLK, 320, 0, stream>>>(weight, code, slots, out);
}

// Round 2
// 3638.593 us; speedup vs baseline: 1.1399x; 1.1399x over previous
//
#include <hip/hip_runtime.h>
#include <stdint.h>

// Net_11587821765063: sequential SNN scan, T=1000 steps.
// Output = spike_out (T, 1, COUT) float32 only; w / traces are not returned.
//
// Math reductions (validated round 1, absmax 0):
//  - potentiation p[t][i] = 2 if x[t][i] else (1 if (t==0 or x[t-1][i]) else 0)
//  - depression for row o at t = -x[t][i] iff (!spike[t][o] && spike[t-1][o]),
//    spike[-1] := true (cout init quirk).
//  - prohibit[t] = 11250 iff any spike at t-1 (grid-wide 1-bit OR).
//
// Sync design (round 2): no barriers, no sync wave, no RMW atomics.
// 512 waves (128 blocks x 4 waves), one output row per wave, 13 cols/lane in
// registers. Per step each wave's lane0 stores ONE byte 0xB0|spike into a
// per-step uint64 slot word (8 rows/word, 64 words/step) at AGENT scope.
// Every wave then polls all 64 words (1 per lane) until every byte has the
// 0xB sentinel nibble, and computes prohibit for t+1 itself (deterministic).
// Store-drain latency is hidden behind the weight update + next-step dot.

#define T_STEPS 1000
#define CIN     784
#define COUT    512
#define CPL     13           // columns per lane (64*13 = 832 >= 784)
#define NBLK    128
#define WPB     4            // waves (rows) per block
#define NWORDS  64           // uint64 slot words per step (512 rows / 8)
#define VTHR_F   12500.0f
#define PROHIB_F 11250.0f

#define SLOTS_BYTES (T_STEPS * NWORDS * 8)    // 512000 B
#define CODE_OFFSET 524288                    // 512 KiB, 16B-aligned
#define CODE_BYTES  (T_STEPS * 64 * 16)       // 1,024,000 B

// ---- prep: zero the slot table and pack per-(t,lane) 16-byte code slot:
// byte j (j<13) encodes col = lane*13+j: bit0 = x[t][col], bits[2:1] = p.
__global__ __launch_bounds__(256) void prep_kernel(const int* __restrict__ x,
                                                   uint8_t* __restrict__ code,
                                                   unsigned long long* __restrict__ slots) {
    int gid = blockIdx.x * blockDim.x + threadIdx.x;   // one per (t, lane)
    if (gid >= T_STEPS * 64) return;
    slots[gid] = 0ull;                                 // T*64 == T*NWORDS
    int t = gid >> 6;
    int lane = gid & 63;
    uint32_t wds[4] = {0u, 0u, 0u, 0u};
    #pragma unroll
    for (int j = 0; j < CPL; ++j) {
        int col = lane * CPL + j;
        uint32_t b = 0u;
        if (col < CIN) {
            int xc = x[t * CIN + col];
            int xp = (t > 0) ? x[(t - 1) * CIN + col] : 0;
            int p = xc ? 2 : ((t == 0) ? 1 : (xp ? 1 : 0));
            b = (uint32_t)((xc & 1) | (p << 1));
        }
        wds[j >> 2] |= b << ((j & 3) * 8);
    }
    ((uint4*)code)[gid] = make_uint4(wds[0], wds[1], wds[2], wds[3]);
}

__device__ __forceinline__ void decode_dot(const uint4& cw, const float* w,
                                           float* xf, float* pf, float& dot) {
    uint32_t cwd[4] = {cw.x, cw.y, cw.z, cw.w};
    dot = 0.0f;
    #pragma unroll
    for (int j = 0; j < CPL; ++j) {
        uint32_t c = (cwd[j >> 2] >> ((j & 3) * 8)) & 0xFFu;
        xf[j] = (float)(c & 1u);
        pf[j] = (float)(c >> 1);
        dot += xf[j] * w[j];          // x is exactly 0/1 -> product exact
    }
    // full-wave butterfly: every lane ends with the row dot
    #pragma unroll
    for (int off = 32; off >= 1; off >>= 1)
        dot += __shfl_xor(dot, off, 64);
}

__global__ __launch_bounds__(256) void snn_kernel(const float* __restrict__ weight,
                                                  const uint8_t* __restrict__ code,
                                                  unsigned long long* __restrict__ slots,
                                                  float* __restrict__ out) {
    const int wave = threadIdx.x >> 6;
    const int lane = threadIdx.x & 63;
    const int row  = blockIdx.x * WPB + wave;

    float w[CPL];
    #pragma unroll
    for (int j = 0; j < CPL; ++j) {
        int col = lane * CPL + j;
        w[j] = (col < CIN) ? weight[row * CIN + col] : 0.0f;
    }

    const uint4* code4 = (const uint4*)code;
    uint4 cwn = code4[64 + lane];      // code for t=1 (prefetch)
    {
        // prologue: dot(0)
    }
    float xf[CPL], pf[CPL];
    float dot;
    {
        uint4 cw0 = code4[lane];
        decode_dot(cw0, w, xf, pf, dot);
    }

    float mem = 0.0f;
    float proh = 0.0f;                 // t=0: reg starts all-false
    bool prevspike = true;             // t=0: cout 0->1 => depression gate open

    const int myword = row >> 3;
    const int mybyte = row & 7;

    for (int t = 0; t < T_STEPS; ++t) {
        // membrane update — exact reference op order
        float m = mem + dot;
        m = m - proh;
        m = fmaxf(m, 0.0f);
        bool spike = (m >= VTHR_F);
        mem = spike ? 0.0f : m;

        if (lane == 0) {
            uint8_t* bp = (uint8_t*)(slots + (size_t)t * NWORDS + myword) + mybyte;
            __hip_atomic_store(bp, (uint8_t)(0xB0u | (spike ? 1u : 0u)),
                               __ATOMIC_RELAXED, __HIP_MEMORY_SCOPE_AGENT);
            out[t * COUT + row] = spike ? 1.0f : 0.0f;
        }

        // weight update for step t (uses xf/pf of step t)
        float sF = spike ? 1.0f : 0.0f;
        float dF = (!spike && prevspike) ? 1.0f : 0.0f;  // mutually exclusive
        prevspike = spike;
        #pragma unroll
        for (int j = 0; j < CPL; ++j) {
            float delta = sF * pf[j] - dF * xf[j];        // exact small ints
            w[j] = fminf(fmaxf(w[j] + delta, 0.0f), 127.0f);
        }

        if (t + 1 < T_STEPS) {
            // compute dot(t+1) with updated weights — overlaps store drain
            uint4 cw2 = (t + 2 < T_STEPS) ? code4[(size_t)(t + 2) * 64 + lane]
                                          : make_uint4(0u, 0u, 0u, 0u);
            decode_dot(cwn, w, xf, pf, dot);
            cwn = cw2;

            // poll step-t spikes from all 512 rows (1 uint64 word per lane)
            const unsigned long long* sl = slots + (size_t)t * NWORDS;
            unsigned long long v;
            bool ok;
            do {
                v = __hip_atomic_load(sl + lane, __ATOMIC_RELAXED,
                                      __HIP_MEMORY_SCOPE_AGENT);
                ok = (v & 0xF0F0F0F0F0F0F0F0ull) == 0xB0B0B0B0B0B0B0B0ull;
            } while (!__all(ok));
            int any = __any((int)((v & 0x0101010101010101ull) != 0ull));
            proh = any ? PROHIB_F : 0.0f;
        }
    }
}

extern "C" void kernel_launch(void* const* d_in, const int* in_sizes, int n_in,
                              void* d_out, int out_size, void* d_ws, size_t ws_size,
                              hipStream_t stream) {
    const int*   x      = (const int*)d_in[0];     // (T,1,CIN) int32
    const float* weight = (const float*)d_in[1];   // (COUT,CIN) f32
    float* out = (float*)d_out;                    // (T,1,COUT) f32

    unsigned long long* slots = (unsigned long long*)d_ws;
    uint8_t*            code  = (uint8_t*)d_ws + CODE_OFFSET;

    int prep_threads = T_STEPS * 64;
    prep_kernel<<<(prep_threads + 255) / 256, 256, 0, stream>>>(x, code, slots);
    snn_kernel<<<NBLK, WPB * 64, 0, stream>>>(weight, code, slots, out);
}

// Round 3
// 2000.256 us; speedup vs baseline: 2.0735x; 1.8191x over previous
//
#include <hip/hip_runtime.h>
#include <stdint.h>

// Net_11587821765063: sequential SNN scan, T=1000 steps.
// Output = spike_out (T,1,COUT) float32 only; w / traces are not returned.
//
// Math reductions (absmax 0 in rounds 1-2):
//  - potentiation p[t][i] = 2 if x[t][i] else (1 if (t==0 or x[t-1][i]) else 0)
//  - depression for row o at t = -x[t][i] iff (!spike[t][o] && spike[t-1][o]),
//    spike[-1] := true (cout init quirk).
//  - prohibit[t] = 11250 iff any spike at t-1 (grid-wide 1-bit OR).
//
// Round 3: 128 waves (128 blocks x 64 thr), 4 rows/wave, 52 w/lane in regs.
// Prohibit SPECULATION: each wave publishes 2 hypothesis bits per step
// (any-row-spike under proh=0 / proh=11250) as ONE byte -> 128 B/step (one
// line). Every wave resolves the prohibit recurrence locally from the
// gathered pairs:  any[t-1] = proh[t-1] ? ANY1[t-1] : ANY0[t-1].
// publish(t) depends on gather(t-2), not gather(t-1) -> one full iteration
// of slack hides most of the MALL round trip. Gather reads the line with
// lanes 0..7 (8B each) -> one MALL transaction per wave per poll.

#define T_STEPS 1000
#define CIN     784
#define COUT    512
#define CPL     13            // columns per lane (64*13 = 832 >= 784)
#define NBLK    128           // one wave per block
#define RPW     4             // rows per wave
#define VTHR_F   12500.0f
#define PROHIB_F 11250.0f

#define SLOTS_BYTES (T_STEPS * 128)           // one 128B line per step
#define CODE_OFFSET 524288                    // 512 KiB, 16B-aligned
#define CODE_BYTES  (T_STEPS * 64 * 16)       // 1,024,000 B

// ---- prep: zero slot lines and pack per-(t,lane) 16-byte code slot:
// byte j (j<13) encodes col = lane*13+j: bit0 = x[t][col], bits[2:1] = p.
__global__ __launch_bounds__(256) void prep_kernel(const int* __restrict__ x,
                                                   uint8_t* __restrict__ code,
                                                   unsigned long long* __restrict__ slots) {
    int gid = blockIdx.x * blockDim.x + threadIdx.x;   // one per (t, lane)
    if (gid >= T_STEPS * 64) return;
    if (gid < SLOTS_BYTES / 8) slots[gid] = 0ull;      // 16000 x 8B = 128000B
    int t = gid >> 6;
    int lane = gid & 63;
    uint32_t wds[4] = {0u, 0u, 0u, 0u};
    #pragma unroll
    for (int j = 0; j < CPL; ++j) {
        int col = lane * CPL + j;
        uint32_t b = 0u;
        if (col < CIN) {
            int xc = x[t * CIN + col];
            int xp = (t > 0) ? x[(t - 1) * CIN + col] : 0;
            int p = xc ? 2 : ((t == 0) ? 1 : (xp ? 1 : 0));
            b = (uint32_t)((xc & 1) | (p << 1));
        }
        wds[j >> 2] |= b << ((j & 3) * 8);
    }
    ((uint4*)code)[gid] = make_uint4(wds[0], wds[1], wds[2], wds[3]);
}

__global__ __launch_bounds__(64) void snn_kernel(const float* __restrict__ weight,
                                                 const uint8_t* __restrict__ code,
                                                 uint8_t* __restrict__ slots,
                                                 float* __restrict__ out) {
    const int lane = threadIdx.x;          // 0..63 (one wave per block)
    const int blk  = blockIdx.x;           // 0..127
    const int row0 = blk * RPW;

    float w[RPW][CPL];
    #pragma unroll
    for (int r = 0; r < RPW; ++r)
        #pragma unroll
        for (int j = 0; j < CPL; ++j) {
            int col = lane * CPL + j;
            w[r][j] = (col < CIN) ? weight[(row0 + r) * CIN + col] : 0.0f;
        }

    const uint4* code4 = (const uint4*)code;
    uint4 cw  = code4[lane];               // codes for t=0
    uint4 cwn = code4[64 + lane];          // codes for t=1 (prefetch)

    float mem[RPW] = {0.0f, 0.0f, 0.0f, 0.0f};
    bool prevspike[RPW] = {true, true, true, true};  // cout init quirk
    bool prohQ = false;                    // proh[t] flag; t=0: reg all-false
    float xf[CPL], pf[CPL];

    for (int t = 0; t < T_STEPS; ++t) {
        // ---- decode codes for step t (shared by all 4 rows) + dots ----
        uint32_t cwd[4] = {cw.x, cw.y, cw.z, cw.w};
        #pragma unroll
        for (int j = 0; j < CPL; ++j) {
            uint32_t c = (cwd[j >> 2] >> ((j & 3) * 8)) & 0xFFu;
            xf[j] = (float)(c & 1u);
            pf[j] = (float)(c >> 1);
        }
        float dot[RPW];
        #pragma unroll
        for (int r = 0; r < RPW; ++r) {
            float d = 0.0f;
            #pragma unroll
            for (int j = 0; j < CPL; ++j) d += xf[j] * w[r][j];  // exact: x in {0,1}
            dot[r] = d;
        }
        // full-wave butterfly per row: every lane ends with the row dot
        #pragma unroll
        for (int off = 32; off >= 1; off >>= 1)
            #pragma unroll
            for (int r = 0; r < RPW; ++r)
                dot[r] += __shfl_xor(dot[r], off, 64);

        // rotate code prefetch
        uint4 cw2 = (t + 2 < T_STEPS) ? code4[(size_t)(t + 2) * 64 + lane]
                                      : make_uint4(0u, 0u, 0u, 0u);
        cw = cwn; cwn = cw2;

        // ---- hypothesis membranes/spikes (proh unknown yet) ----
        float m0[RPW], m1[RPW];
        bool  s0[RPW], s1[RPW];
        bool h0 = false, h1 = false;
        #pragma unroll
        for (int r = 0; r < RPW; ++r) {
            float s = mem[r] + dot[r];                 // reference op order
            m0[r] = fmaxf(s, 0.0f);
            m1[r] = fmaxf(s - PROHIB_F, 0.0f);
            s0[r] = (m0[r] >= VTHR_F);
            s1[r] = (m1[r] >= VTHR_F);
            h0 = h0 || s0[r];
            h1 = h1 || s1[r];
        }
        // ---- publish hypothesis pair for step t (one byte per wave) ----
        if (lane == 0) {
            uint8_t b = (uint8_t)(0xB0u | (h0 ? 1u : 0u) | (h1 ? 2u : 0u));
            __hip_atomic_store(&slots[(size_t)t * 128 + blk], b,
                               __ATOMIC_RELAXED, __HIP_MEMORY_SCOPE_AGENT);
        }

        // ---- resolve proh[t] from step t-1 pairs (published last iter) ----
        if (t > 0) {
            const unsigned long long* sl =
                (const unsigned long long*)(slots + (size_t)(t - 1) * 128);
            unsigned long long v = 0ull;
            bool ok;
            do {
                if (lane < 8)
                    v = __hip_atomic_load(&sl[lane], __ATOMIC_RELAXED,
                                          __HIP_MEMORY_SCOPE_AGENT);
                ok = (lane >= 8) ||
                     ((v & 0xF0F0F0F0F0F0F0F0ull) == 0xB0B0B0B0B0B0B0B0ull);
            } while (!__all(ok));
            int a0 = __any((int)((v & 0x0101010101010101ull) != 0ull));
            int a1 = __any((int)((v & 0x0202020202020202ull) != 0ull));
            bool anyPrev = prohQ ? (a1 != 0) : (a0 != 0);  // uses proh[t-1]
            prohQ = anyPrev;                               // now = proh[t]
        }
        // t == 0: prohQ stays false

        // ---- finalize step t: select actuals, output, weight update ----
        float o[RPW];
        #pragma unroll
        for (int r = 0; r < RPW; ++r) {
            bool sp = prohQ ? s1[r] : s0[r];
            float m = prohQ ? m1[r] : m0[r];
            mem[r] = sp ? 0.0f : m;
            o[r] = sp ? 1.0f : 0.0f;
            if (sp) {                       // potentiate: w=min(w+p,127)
                #pragma unroll
                for (int j = 0; j < CPL; ++j)
                    w[r][j] = fminf(w[r][j] + pf[j], 127.0f);
            } else if (prevspike[r]) {      // depress: w=max(w-x,0)
                #pragma unroll
                for (int j = 0; j < CPL; ++j)
                    w[r][j] = fmaxf(w[r][j] - xf[j], 0.0f);
            }
            prevspike[r] = sp;
        }
        if (lane == 0)
            *((float4*)(out + (size_t)t * COUT + row0)) =
                make_float4(o[0], o[1], o[2], o[3]);
    }
}

extern "C" void kernel_launch(void* const* d_in, const int* in_sizes, int n_in,
                              void* d_out, int out_size, void* d_ws, size_t ws_size,
                              hipStream_t stream) {
    const int*   x      = (const int*)d_in[0];     // (T,1,CIN) int32
    const float* weight = (const float*)d_in[1];   // (COUT,CIN) f32
    float* out = (float*)d_out;                    // (T,1,COUT) f32

    unsigned long long* slots64 = (unsigned long long*)d_ws;
    uint8_t*            slots   = (uint8_t*)d_ws;
    uint8_t*            code    = (uint8_t*)d_ws + CODE_OFFSET;

    int prep_threads = T_STEPS * 64;
    prep_kernel<<<(prep_threads + 255) / 256, 256, 0, stream>>>(x, code, slots64);
    snn_kernel<<<NBLK, 64, 0, stream>>>(weight, code, slots, out);
}

// Round 4
// 1665.348 us; speedup vs baseline: 2.4905x; 1.2011x over previous
//
#include <hip/hip_runtime.h>
#include <stdint.h>

// Net_11587821765063: sequential SNN scan, T=1000 steps.
// Output = spike_out (T,1,COUT) float32 only; w / traces are not returned.
//
// Math reductions (absmax 0 in rounds 1-3):
//  - potentiation p[t][i] = 2 if x[t][i] else (1 if (t==0 or x[t-1][i]) else 0)
//  - depression for row o at t = -x[t][i] iff (!spike[t][o] && spike[t-1][o]),
//    spike[-1] := true (cout init quirk).
//  - prohibit[t] = 11250 iff any spike at t-1 (grid-wide 1-bit OR).
//
// Round 4: hierarchical sync. 32 blocks x 256 threads (4 waves, 1 wave/SIMD).
// Each wave owns 4 rows (13 cols/lane in registers — same compute structure
// as round 3, absmax-0 validated). Per step:
//   waves -> LDS hypothesis bits -> B1 -> wave0 ORs, publishes ONE dword per
//   block (32 dwords = one line grid-wide), polls line(t-1) with a single
//   coalesced 32-lane load, resolves the prohibit recurrence
//   (any[t-1] = proh[t-1] ? ANY1 : ANY0), posts proh via LDS -> B2 -> all
//   waves finalize (select hypothesis, write out, branchy weight update).
// Cross-block speculation gives 1 step of slack: publish(t) depends on
// gather(t-2), so the MALL round trip hides behind local compute.

#define T_STEPS 1000
#define CIN     784
#define COUT    512
#define CPL     13            // columns per lane (64*13 = 832 >= 784)
#define NBLK    32
#define WPB     4             // waves per block
#define RPW     4             // rows per wave (16 rows/block)
#define VTHR_F   12500.0f
#define PROHIB_F 11250.0f

#define SLOTS_WORDS (T_STEPS * NBLK)          // uint32 per (t, blk)
#define SLOTS_BYTES (SLOTS_WORDS * 4)         // 128000 B
#define CODE_OFFSET 524288                    // 512 KiB, 16B-aligned
#define CODE_BYTES  (T_STEPS * 64 * 16)       // 1,024,000 B

// ---- prep: zero slot words and pack per-(t,lane) 16-byte code slot:
// byte j (j<13) encodes col = lane*13+j: bit0 = x[t][col], bits[2:1] = p.
__global__ __launch_bounds__(256) void prep_kernel(const int* __restrict__ x,
                                                   uint8_t* __restrict__ code,
                                                   uint32_t* __restrict__ slots) {
    int gid = blockIdx.x * blockDim.x + threadIdx.x;   // one per (t, lane)
    if (gid >= T_STEPS * 64) return;
    if (gid < SLOTS_WORDS) slots[gid] = 0u;            // 32000 dwords
    int t = gid >> 6;
    int lane = gid & 63;
    uint32_t wds[4] = {0u, 0u, 0u, 0u};
    #pragma unroll
    for (int j = 0; j < CPL; ++j) {
        int col = lane * CPL + j;
        uint32_t b = 0u;
        if (col < CIN) {
            int xc = x[t * CIN + col];
            int xp = (t > 0) ? x[(t - 1) * CIN + col] : 0;
            int p = xc ? 2 : ((t == 0) ? 1 : (xp ? 1 : 0));
            b = (uint32_t)((xc & 1) | (p << 1));
        }
        wds[j >> 2] |= b << ((j & 3) * 8);
    }
    ((uint4*)code)[gid] = make_uint4(wds[0], wds[1], wds[2], wds[3]);
}

__global__ __launch_bounds__(256) void snn_kernel(const float* __restrict__ weight,
                                                  const uint8_t* __restrict__ code,
                                                  uint32_t* __restrict__ slots,
                                                  float* __restrict__ out) {
    __shared__ int   sh_h[WPB];
    __shared__ float sh_proh;

    const int tid  = threadIdx.x;
    const int wave = tid >> 6;
    const int lane = tid & 63;
    const int blk  = blockIdx.x;
    const int row0 = blk * (WPB * RPW) + wave * RPW;

    float w[RPW][CPL];
    #pragma unroll
    for (int r = 0; r < RPW; ++r)
        #pragma unroll
        for (int j = 0; j < CPL; ++j) {
            int col = lane * CPL + j;
            w[r][j] = (col < CIN) ? weight[(row0 + r) * CIN + col] : 0.0f;
        }

    const uint4* code4 = (const uint4*)code;
    uint4 cw  = code4[lane];               // codes for t=0
    uint4 cwn = code4[64 + lane];          // codes for t=1 (prefetch)

    float mem[RPW] = {0.0f, 0.0f, 0.0f, 0.0f};
    bool prevspike[RPW] = {true, true, true, true};  // cout init quirk
    bool prohQ = false;                    // wave0: proh flag recurrence state
    float xf[CPL], pf[CPL];

    for (int t = 0; t < T_STEPS; ++t) {
        // ---- decode codes for step t (shared by the 4 rows) + dots ----
        uint32_t cwd[4] = {cw.x, cw.y, cw.z, cw.w};
        #pragma unroll
        for (int j = 0; j < CPL; ++j) {
            uint32_t c = (cwd[j >> 2] >> ((j & 3) * 8)) & 0xFFu;
            xf[j] = (float)(c & 1u);
            pf[j] = (float)(c >> 1);
        }
        float dot[RPW];
        #pragma unroll
        for (int r = 0; r < RPW; ++r) {
            float d = 0.0f;
            #pragma unroll
            for (int j = 0; j < CPL; ++j) d += xf[j] * w[r][j];  // exact: x in {0,1}
            dot[r] = d;
        }
        #pragma unroll
        for (int off = 32; off >= 1; off >>= 1)
            #pragma unroll
            for (int r = 0; r < RPW; ++r)
                dot[r] += __shfl_xor(dot[r], off, 64);

        // rotate code prefetch
        uint4 cw2 = (t + 2 < T_STEPS) ? code4[(size_t)(t + 2) * 64 + lane]
                                      : make_uint4(0u, 0u, 0u, 0u);
        cw = cwn; cwn = cw2;

        // ---- hypothesis membranes/spikes (proh[t] unknown yet) ----
        float m0[RPW], m1[RPW];
        bool  s0[RPW], s1[RPW];
        bool h0 = false, h1 = false;
        #pragma unroll
        for (int r = 0; r < RPW; ++r) {
            float s = mem[r] + dot[r];                 // reference op order
            m0[r] = fmaxf(s, 0.0f);
            m1[r] = fmaxf(s - PROHIB_F, 0.0f);
            s0[r] = (m0[r] >= VTHR_F);
            s1[r] = (m1[r] >= VTHR_F);
            h0 = h0 || s0[r];
            h1 = h1 || s1[r];
        }
        if (lane == 0) sh_h[wave] = (h0 ? 1 : 0) | (h1 ? 2 : 0);
        __syncthreads();                               // B1

        if (wave == 0) {
            if (lane == 0) {
                int hh = sh_h[0] | sh_h[1] | sh_h[2] | sh_h[3];
                __hip_atomic_store(&slots[t * NBLK + blk],
                                   0xB0u | (uint32_t)hh,
                                   __ATOMIC_RELAXED, __HIP_MEMORY_SCOPE_AGENT);
            }
            if (t > 0) {
                const uint32_t* sl = slots + (size_t)(t - 1) * NBLK;
                uint32_t v = 0xB0u;        // lanes >= NBLK: pass sentinel, 0 bits
                bool ok;
                do {
                    if (lane < NBLK)
                        v = __hip_atomic_load(&sl[lane], __ATOMIC_RELAXED,
                                              __HIP_MEMORY_SCOPE_AGENT);
                    ok = ((v & 0xF0u) == 0xB0u);
                } while (!__all(ok));
                int a0 = __any((int)((v & 1u) != 0u));
                int a1 = __any((int)((v & 2u) != 0u));
                bool anyPrev = prohQ ? (a1 != 0) : (a0 != 0);  // uses proh[t-1]
                prohQ = anyPrev;                               // now = proh[t]
            }
            if (lane == 0) sh_proh = prohQ ? PROHIB_F : 0.0f;
        }
        __syncthreads();                               // B2
        const bool prohB = (sh_proh != 0.0f);

        // ---- finalize step t: select actuals, output, weight update ----
        float o[RPW];
        #pragma unroll
        for (int r = 0; r < RPW; ++r) {
            bool sp = prohB ? s1[r] : s0[r];
            float m = prohB ? m1[r] : m0[r];
            mem[r] = sp ? 0.0f : m;
            o[r] = sp ? 1.0f : 0.0f;
        }
        if (lane == 0)
            *((float4*)(out + (size_t)t * COUT + row0)) =
                make_float4(o[0], o[1], o[2], o[3]);
        #pragma unroll
        for (int r = 0; r < RPW; ++r) {
            bool sp = (o[r] != 0.0f);      // wave-uniform
            if (sp) {                      // potentiate: w=min(w+p,127)
                #pragma unroll
                for (int j = 0; j < CPL; ++j)
                    w[r][j] = fminf(w[r][j] + pf[j], 127.0f);
            } else if (prevspike[r]) {     // depress: w=max(w-x,0)
                #pragma unroll
                for (int j = 0; j < CPL; ++j)
                    w[r][j] = fmaxf(w[r][j] - xf[j], 0.0f);
            }
            prevspike[r] = sp;
        }
    }
}

extern "C" void kernel_launch(void* const* d_in, const int* in_sizes, int n_in,
                              void* d_out, int out_size, void* d_ws, size_t ws_size,
                              hipStream_t stream) {
    const int*   x      = (const int*)d_in[0];     // (T,1,CIN) int32
    const float* weight = (const float*)d_in[1];   // (COUT,CIN) f32
    float* out = (float*)d_out;                    // (T,1,COUT) f32

    uint32_t* slots = (uint32_t*)d_ws;
    uint8_t*  code  = (uint8_t*)d_ws + CODE_OFFSET;

    int prep_threads = T_STEPS * 64;
    prep_kernel<<<(prep_threads + 255) / 256, 256, 0, stream>>>(x, code, slots);
    snn_kernel<<<NBLK, WPB * 64, 0, stream>>>(weight, code, slots, out);
}